// Round 4
// baseline (746.748 us; speedup 1.0000x reference)
//
#include <hip/hip_runtime.h>
#include <hip/hip_bf16.h>
#include <cmath>

// ---------------------------------------------------------------------------
// GAT 2-layer forward.
//  - GEMMs via bf16 MFMA (16x16x32), single-stage LDS, fp32 accumulate.
//  - Edge softmax without max-subtraction (scores are O(1)).
//  - k_agg1 split into 4 channel passes (64 ch each) for L2 locality;
//    edge weights stored plane-major (head-pair planes) so each pass reads
//    a contiguous slice.
//  - CSR scatter done in 8 dst-ranged launches: write window ~850 KB
//    (L2-resident) instead of 6.8 MB of random line-allocating writes.
//  - log_softmax fused into layer-2 aggregation.
// ---------------------------------------------------------------------------

#define LEAKY(e) ((e) >= 0.f ? (e) : 0.2f * (e))

typedef unsigned short ushortT;
typedef unsigned int uintT;
typedef __attribute__((ext_vector_type(8))) short short8;
typedef __attribute__((ext_vector_type(4))) float float4v;

static __device__ __forceinline__ float bf2f(ushortT u) {
    return __uint_as_float(((uintT)u) << 16);
}
static __device__ __forceinline__ float bflo(uintT u) {
    return __uint_as_float(u << 16);
}
static __device__ __forceinline__ float bfhi(uintT u) {
    return __uint_as_float(u & 0xffff0000u);
}
static __device__ __forceinline__ ushortT f2bf(float f) {
    __hip_bfloat16 h = __float2bfloat16(f);   // RNE
    return *reinterpret_cast<ushortT*>(&h);
}

// ---------------- GEMM1: x[M,128] @ W1[128,256] -> bf16 h1b[M,256] ---------
#define LDA1 136   // 128 + 8 pad
__global__ __launch_bounds__(256) void k_gemm1(const float* __restrict__ A,
                                               const float* __restrict__ B,
                                               ushortT* __restrict__ C, int M) {
    __shared__ ushortT As[64 * LDA1];
    __shared__ ushortT Bs[128 * LDA1];
    int tid = threadIdx.x;
    int r0 = blockIdx.y * 64;
    int c0 = blockIdx.x * 128;
    {   // stage A: rows r0..r0+63, k 0..127, fp32 -> bf16
        int row = tid >> 2;
        int kq = (tid & 3) * 32;
        int gr = r0 + row;
        #pragma unroll
        for (int i = 0; i < 8; ++i) {
            int k = kq + i * 4;
            float4 v = (gr < M) ? *(const float4*)(A + (size_t)gr * 128 + k)
                                : make_float4(0.f, 0.f, 0.f, 0.f);
            ushort4 u;
            u.x = f2bf(v.x); u.y = f2bf(v.y); u.z = f2bf(v.z); u.w = f2bf(v.w);
            *(ushort4*)(&As[row * LDA1 + k]) = u;
        }
    }
    {   // stage B: Bs[n][k] = W1[k][c0+n]
        int k = tid >> 1;
        int h = (tid & 1) * 64;
        #pragma unroll
        for (int q = 0; q < 16; ++q) {
            int n = h + q * 4;
            float4 v = *(const float4*)(B + (size_t)k * 256 + c0 + n);
            Bs[(n + 0) * LDA1 + k] = f2bf(v.x);
            Bs[(n + 1) * LDA1 + k] = f2bf(v.y);
            Bs[(n + 2) * LDA1 + k] = f2bf(v.z);
            Bs[(n + 3) * LDA1 + k] = f2bf(v.w);
        }
    }
    __syncthreads();
    int lane = tid & 63, wave = tid >> 6;
    int m15 = lane & 15, quad = lane >> 4;
    int rw = wave * 16;
    float4v acc[8];
    #pragma unroll
    for (int j = 0; j < 8; ++j) acc[j] = (float4v){0.f, 0.f, 0.f, 0.f};
    #pragma unroll
    for (int s = 0; s < 4; ++s) {
        int k0 = s * 32 + quad * 8;
        short8 a = *(const short8*)(&As[(rw + m15) * LDA1 + k0]);
        #pragma unroll
        for (int j = 0; j < 8; ++j) {
            short8 b = *(const short8*)(&Bs[(j * 16 + m15) * LDA1 + k0]);
            acc[j] = __builtin_amdgcn_mfma_f32_16x16x32_bf16(a, b, acc[j], 0, 0, 0);
        }
    }
    #pragma unroll
    for (int j = 0; j < 8; ++j) {
        int col = c0 + j * 16 + m15;
        #pragma unroll
        for (int r = 0; r < 4; ++r) {
            int gr = r0 + rw + quad * 4 + r;
            if (gr < M) C[(size_t)gr * 256 + col] = f2bf(acc[j][r]);
        }
    }
}

// ---------------- scores layer 1: per (n, head) 32-dot over bf16 -----------
__global__ __launch_bounds__(256) void k_scores1(const ushortT* __restrict__ h1,
                                                 const float* __restrict__ a_s,
                                                 const float* __restrict__ a_d,
                                                 float* __restrict__ ss,
                                                 float* __restrict__ sd, int NH) {
    int t = blockIdx.x * blockDim.x + threadIdx.x;
    if (t >= NH) return;
    int h = t & 7;
    const uint4* row = (const uint4*)(h1 + (size_t)t * 32);
    const float* as = a_s + h * 32;
    const float* ad = a_d + h * 32;
    float s1 = 0.f, s2 = 0.f;
    #pragma unroll
    for (int q = 0; q < 4; ++q) {
        uint4 u = row[q];
        uintT w[4] = {u.x, u.y, u.z, u.w};
        #pragma unroll
        for (int k = 0; k < 4; ++k) {
            int c = q * 8 + k * 2;
            s1 += bflo(w[k]) * as[c] + bfhi(w[k]) * as[c + 1];
            s2 += bflo(w[k]) * ad[c] + bfhi(w[k]) * ad[c + 1];
        }
    }
    ss[t] = s1;
    sd[t] = s2;
}

// ---------------- CSR build ------------------------------------------------
__global__ __launch_bounds__(256) void k_deg(const int* __restrict__ ei, int E, int N,
                                             int* __restrict__ deg) {
    int e = blockIdx.x * blockDim.x + threadIdx.x;
    int total = E + N;
    if (e >= total) return;
    int dst = (e < E) ? ei[E + e] : (e - E);
    atomicAdd(&deg[dst], 1);
}

__global__ __launch_bounds__(1024) void k_scan_a(const int* __restrict__ deg,
                                                 int* __restrict__ tmp,
                                                 int* __restrict__ part, int n) {
    __shared__ int wsum[16];
    int t = threadIdx.x, lane = t & 63, wv = t >> 6;
    int i = blockIdx.x * 1024 + t;
    int v = (i < n) ? deg[i] : 0;
    int incl = v;
    #pragma unroll
    for (int off = 1; off < 64; off <<= 1) {
        int u = __shfl_up(incl, off, 64);
        if (lane >= off) incl += u;
    }
    if (lane == 63) wsum[wv] = incl;
    __syncthreads();
    if (wv == 0) {
        int s = (lane < 16) ? wsum[lane] : 0;
        #pragma unroll
        for (int off = 1; off < 16; off <<= 1) {
            int u = __shfl_up(s, off, 64);
            if (lane >= off) s += u;
        }
        if (lane < 16) wsum[lane] = s;
    }
    __syncthreads();
    int g = incl + (wv ? wsum[wv - 1] : 0);
    if (i < n) tmp[i] = g;
    if (t == 1023) part[blockIdx.x] = g;
}

__global__ __launch_bounds__(1024) void k_scan_b(int* __restrict__ part, int nb) {
    __shared__ int wsum[16];
    int t = threadIdx.x, lane = t & 63, wv = t >> 6;
    int v = (t < nb) ? part[t] : 0;
    int incl = v;
    #pragma unroll
    for (int off = 1; off < 64; off <<= 1) {
        int u = __shfl_up(incl, off, 64);
        if (lane >= off) incl += u;
    }
    if (lane == 63) wsum[wv] = incl;
    __syncthreads();
    if (wv == 0) {
        int s = (lane < 16) ? wsum[lane] : 0;
        #pragma unroll
        for (int off = 1; off < 16; off <<= 1) {
            int u = __shfl_up(s, off, 64);
            if (lane >= off) s += u;
        }
        if (lane < 16) wsum[lane] = s;
    }
    __syncthreads();
    int g = incl + (wv ? wsum[wv - 1] : 0);
    if (t < nb) part[t] = g;
}

__global__ __launch_bounds__(256) void k_scan_c(const int* __restrict__ deg,
                                                const int* __restrict__ tmp,
                                                const int* __restrict__ part,
                                                int* __restrict__ rowptr,
                                                int* __restrict__ cursor, int n) {
    int i = blockIdx.x * blockDim.x + threadIdx.x;
    if (i >= n) return;
    int b = i >> 10;
    int off = b ? part[b - 1] : 0;
    int incl = tmp[i] + off;
    rowptr[i + 1] = incl;
    cursor[i] = incl - deg[i];
    if (i == 0) rowptr[0] = 0;
}

// ranged scatter: only edges with dst in [lo,hi) -> write window is
// csr[rowptr[lo]..rowptr[hi]) (~850 KB for 8 ranges), L2-resident.
__global__ __launch_bounds__(256) void k_scatter_r(const int* __restrict__ ei, int E, int N,
                                                   int* __restrict__ cursor,
                                                   int* __restrict__ csr_src,
                                                   int lo, int hi) {
    int e = blockIdx.x * blockDim.x + threadIdx.x;
    int total = E + N;
    if (e >= total) return;
    int dst = (e < E) ? ei[E + e] : (e - E);
    if (dst < lo || dst >= hi) return;
    int src = (e < E) ? ei[e] : dst;
    int pos = atomicAdd(&cursor[dst], 1);
    csr_src[pos] = src;
}

// ---------------- layer-1 weights: wave per dst, 8 edges x 8 heads ---------
// pbuf layout: plane-major, plane p = heads {2p,2p+1}: pbuf[p*ET*2 + i*2 + (h&1)]
__global__ __launch_bounds__(256) void k_wts1(const float* __restrict__ ssrc,
                                              const float* __restrict__ sdst,
                                              const int* __restrict__ rowptr,
                                              const int* __restrict__ csr_src,
                                              ushortT* __restrict__ pbuf,
                                              float* __restrict__ denom, int N, int ET) {
    int lane = threadIdx.x & 63;
    int wid = threadIdx.x >> 6;
    int n = blockIdx.x * 4 + wid;
    if (n >= N) return;
    int head = lane & 7, es = lane >> 3;
    int beg = rowptr[n], end = rowptr[n + 1];
    float sdn = sdst[(size_t)n * 8 + head];
    ushortT* pplane = pbuf + (size_t)(head >> 1) * ET * 2 + (head & 1);
    float l = 0.f;
    for (int i0 = beg; i0 < end; i0 += 8) {
        int i = i0 + es;
        if (i < end) {
            int s = csr_src[i];
            float e = LEAKY(ssrc[(size_t)s * 8 + head] + sdn);
            ushortT pb = f2bf(__expf(e));
            pplane[(size_t)i * 2] = pb;
            l += bf2f(pb);
        }
    }
    l += __shfl_xor(l, 8, 64);
    l += __shfl_xor(l, 16, 64);
    l += __shfl_xor(l, 32, 64);
    if (es == 0) denom[(size_t)n * 8 + head] = l;
}

// ---------------- layer-1 aggregation: channel pass (64 ch), 4 edges/wave --
__global__ __launch_bounds__(256) void k_agg1(const ushortT* __restrict__ h1,
                                              const ushortT* __restrict__ pbuf,
                                              const float* __restrict__ denom,
                                              const int* __restrict__ rowptr,
                                              const int* __restrict__ csr_src,
                                              const float* __restrict__ b1,
                                              ushortT* __restrict__ out1,
                                              int N, int ET, int pass) {
    int lane = threadIdx.x & 63;
    int wid = threadIdx.x >> 6;
    int n = blockIdx.x * 4 + wid;
    if (n >= N) return;
    int slot = lane >> 4, cl = lane & 15;    // 4 edge slots x 16 lanes (4 ch)
    int hq = cl >> 3;                        // head parity within the plane
    int beg = rowptr[n], end = rowptr[n + 1];
    const ushortT* hbase = h1 + pass * 64 + cl * 4;
    const ushortT* pplane = pbuf + (size_t)pass * ET * 2 + hq;
    float a0 = 0.f, a1 = 0.f, a2 = 0.f, a3 = 0.f;
    int idx = beg + slot;
    uint2 vc = make_uint2(0u, 0u);
    float pc = 0.f;
    if (idx < end) {
        int s = csr_src[idx];
        pc = bf2f(pplane[(size_t)idx * 2]);
        vc = *(const uint2*)(hbase + (size_t)s * 256);
    }
    for (; idx < end; idx += 4) {
        uint2 vn = make_uint2(0u, 0u);
        float pn = 0.f;
        int idx2 = idx + 4;
        if (idx2 < end) {
            int s = csr_src[idx2];
            pn = bf2f(pplane[(size_t)idx2 * 2]);
            vn = *(const uint2*)(hbase + (size_t)s * 256);
        }
        a0 += pc * bflo(vc.x);
        a1 += pc * bfhi(vc.x);
        a2 += pc * bflo(vc.y);
        a3 += pc * bfhi(vc.y);
        vc = vn; pc = pn;
    }
    a0 += __shfl_xor(a0, 16, 64);
    a1 += __shfl_xor(a1, 16, 64);
    a2 += __shfl_xor(a2, 16, 64);
    a3 += __shfl_xor(a3, 16, 64);
    a0 += __shfl_xor(a0, 32, 64);
    a1 += __shfl_xor(a1, 32, 64);
    a2 += __shfl_xor(a2, 32, 64);
    a3 += __shfl_xor(a3, 32, 64);
    if (slot == 0) {
        int head = pass * 2 + hq;
        float inv = 1.f / denom[(size_t)n * 8 + head];
        const float4 bb = *(const float4*)(b1 + pass * 64 + cl * 4);
        ushort4 o;
        o.x = f2bf(fmaxf(a0 * inv + bb.x, 0.f));
        o.y = f2bf(fmaxf(a1 * inv + bb.y, 0.f));
        o.z = f2bf(fmaxf(a2 * inv + bb.z, 0.f));
        o.w = f2bf(fmaxf(a3 * inv + bb.w, 0.f));
        *(ushort4*)(out1 + (size_t)n * 256 + pass * 64 + cl * 4) = o;
    }
}

// ---------------- GEMM2: out1b[M,256] @ W2[256,40] -> bf16 h2b[M,40] -------
#define LDA2 264   // 256 + 8 pad
__global__ __launch_bounds__(256) void k_gemm2(const ushortT* __restrict__ X,
                                               const float* __restrict__ W,
                                               ushortT* __restrict__ H2, int M) {
    __shared__ ushortT As[64 * LDA2];
    __shared__ ushortT Bs[48 * LDA2];
    int tid = threadIdx.x;
    int r0 = blockIdx.x * 64;
    {
        int row = tid >> 2;
        int kq = (tid & 3) * 64;
        int gr = r0 + row;
        #pragma unroll
        for (int i = 0; i < 8; ++i) {
            int k = kq + i * 8;
            uint4 v = (gr < M) ? *(const uint4*)(X + (size_t)gr * 256 + k)
                               : make_uint4(0u, 0u, 0u, 0u);
            *(uint4*)(&As[row * LDA2 + k]) = v;
        }
    }
    {
        int k = tid;
        #pragma unroll
        for (int q = 0; q < 10; ++q) {
            float4 v = *(const float4*)(W + (size_t)k * 40 + q * 4);
            Bs[(q * 4 + 0) * LDA2 + k] = f2bf(v.x);
            Bs[(q * 4 + 1) * LDA2 + k] = f2bf(v.y);
            Bs[(q * 4 + 2) * LDA2 + k] = f2bf(v.z);
            Bs[(q * 4 + 3) * LDA2 + k] = f2bf(v.w);
        }
        #pragma unroll
        for (int n = 40; n < 48; ++n) Bs[n * LDA2 + k] = 0;
    }
    __syncthreads();
    int lane = tid & 63, wave = tid >> 6;
    int m15 = lane & 15, quad = lane >> 4;
    int rw = wave * 16;
    float4v acc[3];
    #pragma unroll
    for (int j = 0; j < 3; ++j) acc[j] = (float4v){0.f, 0.f, 0.f, 0.f};
    #pragma unroll
    for (int s = 0; s < 8; ++s) {
        int k0 = s * 32 + quad * 8;
        short8 a = *(const short8*)(&As[(rw + m15) * LDA2 + k0]);
        #pragma unroll
        for (int j = 0; j < 3; ++j) {
            short8 b = *(const short8*)(&Bs[(j * 16 + m15) * LDA2 + k0]);
            acc[j] = __builtin_amdgcn_mfma_f32_16x16x32_bf16(a, b, acc[j], 0, 0, 0);
        }
    }
    #pragma unroll
    for (int j = 0; j < 3; ++j) {
        int col = j * 16 + m15;
        if (col >= 40) continue;
        #pragma unroll
        for (int r = 0; r < 4; ++r) {
            int gr = r0 + rw + quad * 4 + r;
            if (gr < M) H2[(size_t)gr * 40 + col] = f2bf(acc[j][r]);
        }
    }
}

// ---------------- scores layer 2: per node 40-dot --------------------------
__global__ __launch_bounds__(256) void k_scores2(const ushortT* __restrict__ h2,
                                                 const float* __restrict__ a2s,
                                                 const float* __restrict__ a2d,
                                                 float* __restrict__ ss,
                                                 float* __restrict__ sd, int N) {
    int n = blockIdx.x * blockDim.x + threadIdx.x;
    if (n >= N) return;
    const uint4* row = (const uint4*)(h2 + (size_t)n * 40);
    float s1 = 0.f, s2 = 0.f;
    #pragma unroll
    for (int q = 0; q < 5; ++q) {
        uint4 u = row[q];
        uintT w[4] = {u.x, u.y, u.z, u.w};
        #pragma unroll
        for (int k = 0; k < 4; ++k) {
            int c = q * 8 + k * 2;
            s1 += bflo(w[k]) * a2s[c] + bfhi(w[k]) * a2s[c + 1];
            s2 += bflo(w[k]) * a2d[c] + bfhi(w[k]) * a2d[c + 1];
        }
    }
    ss[n] = s1;
    sd[n] = s2;
}

// ---------------- layer-2 weights: wave per dst (no max pass) --------------
__global__ __launch_bounds__(256) void k_wts2(const float* __restrict__ ss,
                                              const float* __restrict__ sd,
                                              const int* __restrict__ rowptr,
                                              const int* __restrict__ csr_src,
                                              float* __restrict__ pbuf,
                                              float* __restrict__ denom, int N) {
    int lane = threadIdx.x & 63;
    int wid = threadIdx.x >> 6;
    int n = blockIdx.x * 4 + wid;
    if (n >= N) return;
    int beg = rowptr[n], end = rowptr[n + 1];
    float sdn = sd[n];
    float l = 0.f;
    for (int i0 = beg; i0 < end; i0 += 64) {
        int i = i0 + lane;
        if (i < end) {
            float e = LEAKY(ss[csr_src[i]] + sdn);
            float p = __expf(e);
            pbuf[i] = p;
            l += p;
        }
    }
    #pragma unroll
    for (int off = 1; off < 64; off <<= 1) l += __shfl_xor(l, off, 64);
    if (lane == 0) denom[n] = l;
}

// ---------------- layer-2 aggregation + fused log_softmax ------------------
__global__ __launch_bounds__(256) void k_agg2lsm(const ushortT* __restrict__ h2,
                                                 const float* __restrict__ pbuf,
                                                 const float* __restrict__ denom,
                                                 const int* __restrict__ rowptr,
                                                 const int* __restrict__ csr_src,
                                                 const float* __restrict__ b2,
                                                 float* __restrict__ out, int N) {
    int lane = threadIdx.x & 63;
    int wid = threadIdx.x >> 6;
    int n = blockIdx.x * 4 + wid;
    if (n >= N) return;
    int el = lane / 10;
    int cl = lane - el * 10;
    bool act = (el < 6);
    int beg = rowptr[n], end = rowptr[n + 1];
    float a0 = 0.f, a1 = 0.f, a2 = 0.f, a3 = 0.f;
    if (act) {
        int idx = beg + el;
        uint2 vc = make_uint2(0u, 0u);
        float pc = 0.f;
        if (idx < end) {
            int s = csr_src[idx];
            pc = pbuf[idx];
            vc = *(const uint2*)(h2 + (size_t)s * 40 + cl * 4);
        }
        for (; idx < end; idx += 6) {
            uint2 vn = make_uint2(0u, 0u);
            float pn = 0.f;
            int idx2 = idx + 6;
            if (idx2 < end) {
                int s = csr_src[idx2];
                pn = pbuf[idx2];
                vn = *(const uint2*)(h2 + (size_t)s * 40 + cl * 4);
            }
            a0 += pc * bflo(vc.x);
            a1 += pc * bfhi(vc.x);
            a2 += pc * bflo(vc.y);
            a3 += pc * bfhi(vc.y);
            vc = vn; pc = pn;
        }
    }
    float t0 = 0.f, t1 = 0.f, t2 = 0.f, t3 = 0.f;
    #pragma unroll
    for (int k = 0; k < 6; ++k) {
        int srcl = cl + 10 * k;
        t0 += __shfl(a0, srcl, 64);
        t1 += __shfl(a1, srcl, 64);
        t2 += __shfl(a2, srcl, 64);
        t3 += __shfl(a3, srcl, 64);
    }
    float inv = 1.f / denom[n];
    float o0 = t0 * inv + b2[cl * 4 + 0];
    float o1 = t1 * inv + b2[cl * 4 + 1];
    float o2 = t2 * inv + b2[cl * 4 + 2];
    float o3 = t3 * inv + b2[cl * 4 + 3];
    float lm = (lane < 10) ? fmaxf(fmaxf(o0, o1), fmaxf(o2, o3)) : -INFINITY;
    #pragma unroll
    for (int off = 32; off; off >>= 1) lm = fmaxf(lm, __shfl_xor(lm, off, 64));
    float le = (lane < 10)
        ? __expf(o0 - lm) + __expf(o1 - lm) + __expf(o2 - lm) + __expf(o3 - lm)
        : 0.f;
    #pragma unroll
    for (int off = 32; off; off >>= 1) le += __shfl_xor(le, off, 64);
    float ls = lm + logf(le);
    if (lane < 10) {
        float4 w = make_float4(o0 - ls, o1 - ls, o2 - ls, o3 - ls);
        *(float4*)(out + (size_t)n * 40 + cl * 4) = w;
    }
}

// ---------------------------------------------------------------------------
extern "C" void kernel_launch(void* const* d_in, const int* in_sizes, int n_in,
                              void* d_out, int out_size, void* d_ws, size_t ws_size,
                              hipStream_t stream) {
    const float* x   = (const float*)d_in[0];
    const int*   ei  = (const int*)d_in[1];
    const float* W1  = (const float*)d_in[2];
    const float* a1s = (const float*)d_in[3];
    const float* a1d = (const float*)d_in[4];
    const float* b1  = (const float*)d_in[5];
    const float* W2  = (const float*)d_in[6];
    const float* a2s = (const float*)d_in[7];
    const float* a2d = (const float*)d_in[8];
    const float* b2  = (const float*)d_in[9];
    float* out = (float*)d_out;

    const int N = in_sizes[0] / 128;   // 100000
    const int E = in_sizes[1] / 2;     // 1600000
    const int ET = E + N;

    // ---- workspace layout ----
    char* w = (char*)d_ws;
    ushortT* h1b   = (ushortT*)w;                         // N*256 bf16
    ushortT* out1b = h1b + (size_t)N * 256;               // N*256 bf16
    float* s1s  = (float*)(out1b + (size_t)N * 256);      // N*8
    float* s1d  = s1s + (size_t)N * 8;
    float* den1 = s1d + (size_t)N * 8;
    ushortT* p1b = (ushortT*)(den1 + (size_t)N * 8);      // 4 planes x ET x 2 bf16
    int* i_deg = (int*)(p1b + (size_t)ET * 8);
    int* i_row = i_deg + (N + 16);
    int* i_cur = i_row + (N + 16);
    int* i_tmp = i_cur + (N + 16);
    int* i_par = i_tmp + (N + 16);
    int* i_csr = i_par + 2048;                            // ET ints
    // layer-2 buffers overlay h1b (dead after k_agg1 passes)
    ushortT* h2b = (ushortT*)w;                           // N*40 bf16
    float* p2   = (float*)(w + (size_t)N * 40 * 2);       // ET f32
    float* s2s  = p2 + ET;
    float* s2d  = s2s + N;
    float* den2 = s2d + N;

    const int nb4 = (N + 3) / 4;
    const int nbs = (N + 1023) / 1024;

    // ---- CSR build ----
    hipMemsetAsync(i_deg, 0, (size_t)N * sizeof(int), stream);
    k_deg<<<(ET + 255) / 256, 256, 0, stream>>>(ei, E, N, i_deg);
    k_scan_a<<<nbs, 1024, 0, stream>>>(i_deg, i_tmp, i_par, N);
    k_scan_b<<<1, 1024, 0, stream>>>(i_par, nbs);
    k_scan_c<<<(N + 255) / 256, 256, 0, stream>>>(i_deg, i_tmp, i_par, i_row, i_cur, N);
    {   // ranged scatter: 8 sequential dst ranges for write locality
        const int P = 8;
        int step = (N + P - 1) / P;
        for (int p = 0; p < P; ++p) {
            int lo = p * step;
            int hi = min(N, lo + step);
            k_scatter_r<<<(ET + 255) / 256, 256, 0, stream>>>(ei, E, N, i_cur, i_csr, lo, hi);
        }
    }

    // ---- layer 1 ----
    {
        dim3 grid(2, (N + 63) / 64);
        k_gemm1<<<grid, 256, 0, stream>>>(x, W1, h1b, N);
    }
    k_scores1<<<(N * 8 + 255) / 256, 256, 0, stream>>>(h1b, a1s, a1d, s1s, s1d, N * 8);
    k_wts1<<<nb4, 256, 0, stream>>>(s1s, s1d, i_row, i_csr, p1b, den1, N, ET);
    for (int pass = 0; pass < 4; ++pass)
        k_agg1<<<nb4, 256, 0, stream>>>(h1b, p1b, den1, i_row, i_csr, b1, out1b, N, ET, pass);

    // ---- layer 2 ----
    k_gemm2<<<(N + 63) / 64, 256, 0, stream>>>(out1b, W2, h2b, N);
    k_scores2<<<(N + 255) / 256, 256, 0, stream>>>(h2b, a2s, a2d, s2s, s2d, N);
    k_wts2<<<nb4, 256, 0, stream>>>(s2s, s2d, i_row, i_csr, p2, den2, N);
    k_agg2lsm<<<nb4, 256, 0, stream>>>(h2b, p2, den2, i_row, i_csr, b2, out, N);
}

// Round 5
// 658.916 us; speedup vs baseline: 1.1333x; 1.1333x over previous
//
#include <hip/hip_runtime.h>
#include <hip/hip_bf16.h>
#include <cmath>

// ---------------------------------------------------------------------------
// GAT 2-layer forward.
//  - LDS-free MFMA GEMMs: A-frags loaded direct global->reg (contiguous 16B
//    per lane, full-line coalesced per wave); B-frags from pre-transposed
//    bf16 weights (L1-hot). No barriers; tail waves early-exit.
//  - Softmax weights computed INLINE in aggregation (denominator accumulated
//    alongside) -> no edge-weight buffer, no wts kernels.
//  - CSR counting sort; scatter in 2 dst-ranged passes (write window ~3.4 MB).
//  - scores2 fused into GEMM2 epilogue; log_softmax fused into agg2.
// ---------------------------------------------------------------------------

#define LEAKY(e) ((e) >= 0.f ? (e) : 0.2f * (e))

typedef unsigned short ushortT;
typedef unsigned int uintT;
typedef __attribute__((ext_vector_type(8))) short short8;
typedef __attribute__((ext_vector_type(4))) float float4v;

static __device__ __forceinline__ float bf2f(ushortT u) {
    return __uint_as_float(((uintT)u) << 16);
}
static __device__ __forceinline__ float bflo(uintT u) {
    return __uint_as_float(u << 16);
}
static __device__ __forceinline__ float bfhi(uintT u) {
    return __uint_as_float(u & 0xffff0000u);
}
static __device__ __forceinline__ ushortT f2bf(float f) {
    __hip_bfloat16 h = __float2bfloat16(f);   // RNE
    return *reinterpret_cast<ushortT*>(&h);
}

// ---------------- prep: transpose weights to bf16 --------------------------
// W1t[c][k] (c<256,k<128);  W2t[c][k] (c<48 zero-padded, k<256)
__global__ __launch_bounds__(256) void k_prep(const float* __restrict__ W1,
                                              const float* __restrict__ W2,
                                              ushortT* __restrict__ W1t,
                                              ushortT* __restrict__ W2t) {
    int t = blockIdx.x * 256 + threadIdx.x;
    if (t < 128 * 256) {
        int k = t >> 8, c = t & 255;
        W1t[c * 128 + k] = f2bf(W1[t]);
    } else {
        int q = t - 128 * 256;
        if (q < 48 * 256) {
            int k = q / 48, c = q - k * 48;
            W2t[c * 256 + k] = (c < 40) ? f2bf(W2[k * 40 + c]) : (ushortT)0;
        }
    }
}

// ---------------- GEMM1: x[M,128] @ W1 -> bf16 h1b[M,256] ------------------
// wave computes 16 rows x 256 cols; no LDS.
__global__ __launch_bounds__(256) void k_gemm1(const float* __restrict__ A,
                                               const ushortT* __restrict__ Bt,
                                               ushortT* __restrict__ C, int M) {
    int lane = threadIdx.x & 63, wave = threadIdx.x >> 6;
    int slab = blockIdx.x * 4 + wave;
    int r0 = slab * 16;
    if (r0 >= M) return;
    int n = lane & 15, q = lane >> 4;
    const float* arow = A + (size_t)(r0 + n) * 128 + q * 8;
    short8 af[4];
    #pragma unroll
    for (int s = 0; s < 4; ++s) {
        float4 v0 = *(const float4*)(arow + s * 32);
        float4 v1 = *(const float4*)(arow + s * 32 + 4);
        short8 a;
        a[0] = (short)f2bf(v0.x); a[1] = (short)f2bf(v0.y);
        a[2] = (short)f2bf(v0.z); a[3] = (short)f2bf(v0.w);
        a[4] = (short)f2bf(v1.x); a[5] = (short)f2bf(v1.y);
        a[6] = (short)f2bf(v1.z); a[7] = (short)f2bf(v1.w);
        af[s] = a;
    }
    float4v acc[16];
    #pragma unroll
    for (int j = 0; j < 16; ++j) acc[j] = (float4v){0.f, 0.f, 0.f, 0.f};
    #pragma unroll
    for (int s = 0; s < 4; ++s) {
        #pragma unroll
        for (int j = 0; j < 16; ++j) {
            short8 b = *(const short8*)(Bt + (size_t)(j * 16 + n) * 128 + s * 32 + q * 8);
            acc[j] = __builtin_amdgcn_mfma_f32_16x16x32_bf16(af[s], b, acc[j], 0, 0, 0);
        }
    }
    #pragma unroll
    for (int j = 0; j < 16; ++j) {
        int col = j * 16 + n;
        #pragma unroll
        for (int r = 0; r < 4; ++r)
            C[(size_t)(r0 + q * 4 + r) * 256 + col] = f2bf(acc[j][r]);
    }
}

// ---------------- scores layer 1: per (n, head) 32-dot over bf16 -----------
__global__ __launch_bounds__(256) void k_scores1(const ushortT* __restrict__ h1,
                                                 const float* __restrict__ a_s,
                                                 const float* __restrict__ a_d,
                                                 float* __restrict__ ss,
                                                 float* __restrict__ sd, int NH) {
    int t = blockIdx.x * blockDim.x + threadIdx.x;
    if (t >= NH) return;
    int h = t & 7;
    const uint4* row = (const uint4*)(h1 + (size_t)t * 32);
    const float* as = a_s + h * 32;
    const float* ad = a_d + h * 32;
    float s1 = 0.f, s2 = 0.f;
    #pragma unroll
    for (int q = 0; q < 4; ++q) {
        uint4 u = row[q];
        uintT w[4] = {u.x, u.y, u.z, u.w};
        #pragma unroll
        for (int k = 0; k < 4; ++k) {
            int c = q * 8 + k * 2;
            s1 += bflo(w[k]) * as[c] + bfhi(w[k]) * as[c + 1];
            s2 += bflo(w[k]) * ad[c] + bfhi(w[k]) * ad[c + 1];
        }
    }
    ss[t] = s1;
    sd[t] = s2;
}

// ---------------- CSR build ------------------------------------------------
__global__ __launch_bounds__(256) void k_deg(const int* __restrict__ ei, int E, int N,
                                             int* __restrict__ deg) {
    int e = blockIdx.x * blockDim.x + threadIdx.x;
    int total = E + N;
    if (e >= total) return;
    int dst = (e < E) ? ei[E + e] : (e - E);
    atomicAdd(&deg[dst], 1);
}

__global__ __launch_bounds__(1024) void k_scan_a(const int* __restrict__ deg,
                                                 int* __restrict__ tmp,
                                                 int* __restrict__ part, int n) {
    __shared__ int wsum[16];
    int t = threadIdx.x, lane = t & 63, wv = t >> 6;
    int i = blockIdx.x * 1024 + t;
    int v = (i < n) ? deg[i] : 0;
    int incl = v;
    #pragma unroll
    for (int off = 1; off < 64; off <<= 1) {
        int u = __shfl_up(incl, off, 64);
        if (lane >= off) incl += u;
    }
    if (lane == 63) wsum[wv] = incl;
    __syncthreads();
    if (wv == 0) {
        int s = (lane < 16) ? wsum[lane] : 0;
        #pragma unroll
        for (int off = 1; off < 16; off <<= 1) {
            int u = __shfl_up(s, off, 64);
            if (lane >= off) s += u;
        }
        if (lane < 16) wsum[lane] = s;
    }
    __syncthreads();
    int g = incl + (wv ? wsum[wv - 1] : 0);
    if (i < n) tmp[i] = g;
    if (t == 1023) part[blockIdx.x] = g;
}

__global__ __launch_bounds__(1024) void k_scan_b(int* __restrict__ part, int nb) {
    __shared__ int wsum[16];
    int t = threadIdx.x, lane = t & 63, wv = t >> 6;
    int v = (t < nb) ? part[t] : 0;
    int incl = v;
    #pragma unroll
    for (int off = 1; off < 64; off <<= 1) {
        int u = __shfl_up(incl, off, 64);
        if (lane >= off) incl += u;
    }
    if (lane == 63) wsum[wv] = incl;
    __syncthreads();
    if (wv == 0) {
        int s = (lane < 16) ? wsum[lane] : 0;
        #pragma unroll
        for (int off = 1; off < 16; off <<= 1) {
            int u = __shfl_up(s, off, 64);
            if (lane >= off) s += u;
        }
        if (lane < 16) wsum[lane] = s;
    }
    __syncthreads();
    int g = incl + (wv ? wsum[wv - 1] : 0);
    if (t < nb) part[t] = g;
}

__global__ __launch_bounds__(256) void k_scan_c(const int* __restrict__ deg,
                                                const int* __restrict__ tmp,
                                                const int* __restrict__ part,
                                                int* __restrict__ rowptr,
                                                int* __restrict__ cursor, int n) {
    int i = blockIdx.x * blockDim.x + threadIdx.x;
    if (i >= n) return;
    int b = i >> 10;
    int off = b ? part[b - 1] : 0;
    int incl = tmp[i] + off;
    rowptr[i + 1] = incl;
    cursor[i] = incl - deg[i];
    if (i == 0) rowptr[0] = 0;
}

__global__ __launch_bounds__(256) void k_scatter_r(const int* __restrict__ ei, int E, int N,
                                                   int* __restrict__ cursor,
                                                   int* __restrict__ csr_src,
                                                   int lo, int hi) {
    int e = blockIdx.x * blockDim.x + threadIdx.x;
    int total = E + N;
    if (e >= total) return;
    int dst = (e < E) ? ei[E + e] : (e - E);
    if (dst < lo || dst >= hi) return;
    int src = (e < E) ? ei[e] : dst;
    int pos = atomicAdd(&cursor[dst], 1);
    csr_src[pos] = src;
}

// ---------------- layer-1 aggregation, inline softmax ----------------------
// wave per dst node; lane -> 4 ch (head = lane>>3); p computed in-register,
// denominator accumulated alongside (normalize after loop).
__global__ __launch_bounds__(256) void k_agg1(const ushortT* __restrict__ h1,
                                              const float* __restrict__ ssrc,
                                              const float* __restrict__ sdst,
                                              const int* __restrict__ rowptr,
                                              const int* __restrict__ csr_src,
                                              const float* __restrict__ b1,
                                              ushortT* __restrict__ out1, int N) {
    int lane = threadIdx.x & 63;
    int wid = threadIdx.x >> 6;
    int n = blockIdx.x * 4 + wid;
    if (n >= N) return;
    int head = lane >> 3;
    int beg = rowptr[n], end = rowptr[n + 1];
    float sdn = sdst[(size_t)n * 8 + head];
    float a0 = 0.f, a1 = 0.f, a2 = 0.f, a3 = 0.f, l = 0.f;
    float sv_n = 0.f;
    uint2 v_n = make_uint2(0u, 0u);
    if (beg < end) {
        int s = csr_src[beg];
        sv_n = ssrc[(size_t)s * 8 + head];
        v_n = ((const uint2*)(h1 + (size_t)s * 256))[lane];
    }
    for (int idx = beg; idx < end; ++idx) {
        float sv = sv_n;
        uint2 v = v_n;
        if (idx + 1 < end) {
            int s = csr_src[idx + 1];
            sv_n = ssrc[(size_t)s * 8 + head];
            v_n = ((const uint2*)(h1 + (size_t)s * 256))[lane];
        }
        float e = LEAKY(sv + sdn);
        float p = __expf(e);
        l += p;
        a0 += p * bflo(v.x);
        a1 += p * bfhi(v.x);
        a2 += p * bflo(v.y);
        a3 += p * bfhi(v.y);
    }
    float inv = 1.f / l;
    const float4 bb = *(const float4*)(b1 + lane * 4);
    ushort4 o;
    o.x = f2bf(fmaxf(a0 * inv + bb.x, 0.f));
    o.y = f2bf(fmaxf(a1 * inv + bb.y, 0.f));
    o.z = f2bf(fmaxf(a2 * inv + bb.z, 0.f));
    o.w = f2bf(fmaxf(a3 * inv + bb.w, 0.f));
    *(ushort4*)(out1 + (size_t)n * 256 + lane * 4) = o;
}

// ---------------- GEMM2: out1b[M,256] @ W2 -> bf16 h2b[M,40] + scores2 -----
__global__ __launch_bounds__(256) void k_gemm2(const ushortT* __restrict__ X,
                                               const ushortT* __restrict__ Bt,
                                               const float* __restrict__ a2s,
                                               const float* __restrict__ a2d,
                                               ushortT* __restrict__ H2,
                                               float* __restrict__ s2s,
                                               float* __restrict__ s2d, int M) {
    int lane = threadIdx.x & 63, wave = threadIdx.x >> 6;
    int slab = blockIdx.x * 4 + wave;
    int r0 = slab * 16;
    if (r0 >= M) return;
    int n = lane & 15, q = lane >> 4;
    const ushortT* xrow = X + (size_t)(r0 + n) * 256 + q * 8;
    float4v acc[3];
    #pragma unroll
    for (int j = 0; j < 3; ++j) acc[j] = (float4v){0.f, 0.f, 0.f, 0.f};
    #pragma unroll
    for (int s = 0; s < 8; ++s) {
        short8 a = *(const short8*)(xrow + s * 32);
        #pragma unroll
        for (int j = 0; j < 3; ++j) {
            short8 b = *(const short8*)(Bt + (size_t)(j * 16 + n) * 256 + s * 32 + q * 8);
            acc[j] = __builtin_amdgcn_mfma_f32_16x16x32_bf16(a, b, acc[j], 0, 0, 0);
        }
    }
    // fused scores2: per-row 40-dot with a2s/a2d, reduced over the 16 lanes
    float asv[3], adv[3];
    #pragma unroll
    for (int j = 0; j < 3; ++j) {
        int col = j * 16 + n;
        asv[j] = (col < 40) ? a2s[col] : 0.f;
        adv[j] = (col < 40) ? a2d[col] : 0.f;
    }
    float us[4], ud[4];
    #pragma unroll
    for (int r = 0; r < 4; ++r) {
        us[r] = acc[0][r] * asv[0] + acc[1][r] * asv[1] + acc[2][r] * asv[2];
        ud[r] = acc[0][r] * adv[0] + acc[1][r] * adv[1] + acc[2][r] * adv[2];
    }
    #pragma unroll
    for (int off = 1; off < 16; off <<= 1) {
        #pragma unroll
        for (int r = 0; r < 4; ++r) {
            us[r] += __shfl_xor(us[r], off, 64);
            ud[r] += __shfl_xor(ud[r], off, 64);
        }
    }
    #pragma unroll
    for (int j = 0; j < 3; ++j) {
        int col = j * 16 + n;
        if (col < 40) {
            #pragma unroll
            for (int r = 0; r < 4; ++r)
                H2[(size_t)(r0 + q * 4 + r) * 40 + col] = f2bf(acc[j][r]);
        }
    }
    if (n == 0) {
        #pragma unroll
        for (int r = 0; r < 4; ++r) {
            int row = r0 + q * 4 + r;
            s2s[row] = us[r];
            s2d[row] = ud[r];
        }
    }
}

// ---------------- layer-2 aggregation, inline softmax + log_softmax --------
__global__ __launch_bounds__(256) void k_agg2lsm(const ushortT* __restrict__ h2,
                                                 const float* __restrict__ ss,
                                                 const float* __restrict__ sd,
                                                 const int* __restrict__ rowptr,
                                                 const int* __restrict__ csr_src,
                                                 const float* __restrict__ b2,
                                                 float* __restrict__ out, int N) {
    int lane = threadIdx.x & 63;
    int wid = threadIdx.x >> 6;
    int n = blockIdx.x * 4 + wid;
    if (n >= N) return;
    int el = lane / 10;
    int cl = lane - el * 10;
    int beg = rowptr[n], end = rowptr[n + 1];
    float sdn = sd[n];
    float a0 = 0.f, a1 = 0.f, a2 = 0.f, a3 = 0.f, l = 0.f;
    if (el < 6) {
        int idx = beg + el;
        float sv_n = 0.f;
        uint2 v_n = make_uint2(0u, 0u);
        if (idx < end) {
            int s = csr_src[idx];
            sv_n = ss[s];
            v_n = *(const uint2*)(h2 + (size_t)s * 40 + cl * 4);
        }
        for (; idx < end; idx += 6) {
            float sv = sv_n;
            uint2 v = v_n;
            int idx2 = idx + 6;
            if (idx2 < end) {
                int s = csr_src[idx2];
                sv_n = ss[s];
                v_n = *(const uint2*)(h2 + (size_t)s * 40 + cl * 4);
            }
            float p = __expf(LEAKY(sv + sdn));
            l += p;
            a0 += p * bflo(v.x);
            a1 += p * bfhi(v.x);
            a2 += p * bflo(v.y);
            a3 += p * bfhi(v.y);
        }
    }
    // reduce the 6 slots into lanes 0..9 (l is slot-uniform)
    float t0 = 0.f, t1 = 0.f, t2 = 0.f, t3 = 0.f, lt = 0.f;
    #pragma unroll
    for (int k = 0; k < 6; ++k) {
        int sl = cl + 10 * k;
        t0 += __shfl(a0, sl, 64);
        t1 += __shfl(a1, sl, 64);
        t2 += __shfl(a2, sl, 64);
        t3 += __shfl(a3, sl, 64);
        if (cl == 0) lt += __shfl(l, sl, 64);
    }
    lt = __shfl(lt, (lane / 10) * 0, 64);   // broadcast lane 0's sum? no:
    // recompute properly: every lane needs lt; take it from lane 0 group
    // (cl==0 lanes hold it). Broadcast from lane 0:
    lt = __shfl(lt, 0, 64);
    float inv = 1.f / lt;
    float o0 = t0 * inv + b2[cl * 4 + 0];
    float o1 = t1 * inv + b2[cl * 4 + 1];
    float o2 = t2 * inv + b2[cl * 4 + 2];
    float o3 = t3 * inv + b2[cl * 4 + 3];
    float lm = (lane < 10) ? fmaxf(fmaxf(o0, o1), fmaxf(o2, o3)) : -INFINITY;
    #pragma unroll
    for (int off = 32; off; off >>= 1) lm = fmaxf(lm, __shfl_xor(lm, off, 64));
    float le = (lane < 10)
        ? __expf(o0 - lm) + __expf(o1 - lm) + __expf(o2 - lm) + __expf(o3 - lm)
        : 0.f;
    #pragma unroll
    for (int off = 32; off; off >>= 1) le += __shfl_xor(le, off, 64);
    float ls = lm + logf(le);
    if (lane < 10) {
        float4 w = make_float4(o0 - ls, o1 - ls, o2 - ls, o3 - ls);
        *(float4*)(out + (size_t)n * 40 + cl * 4) = w;
    }
}

// ---------------------------------------------------------------------------
extern "C" void kernel_launch(void* const* d_in, const int* in_sizes, int n_in,
                              void* d_out, int out_size, void* d_ws, size_t ws_size,
                              hipStream_t stream) {
    const float* x   = (const float*)d_in[0];
    const int*   ei  = (const int*)d_in[1];
    const float* W1  = (const float*)d_in[2];
    const float* a1s = (const float*)d_in[3];
    const float* a1d = (const float*)d_in[4];
    const float* b1  = (const float*)d_in[5];
    const float* W2  = (const float*)d_in[6];
    const float* a2s = (const float*)d_in[7];
    const float* a2d = (const float*)d_in[8];
    const float* b2  = (const float*)d_in[9];
    float* out = (float*)d_out;

    const int N = in_sizes[0] / 128;   // 100000
    const int E = in_sizes[1] / 2;     // 1600000
    const int ET = E + N;

    // ---- workspace layout ----
    char* w = (char*)d_ws;
    ushortT* h1b   = (ushortT*)w;                         // N*256 bf16 (51.2 MB)
    ushortT* out1b = h1b + (size_t)N * 256;               // N*256 bf16 (51.2 MB)
    float* s1s  = (float*)(out1b + (size_t)N * 256);      // N*8
    float* s1d  = s1s + (size_t)N * 8;
    int* i_deg = (int*)(s1d + (size_t)N * 8);
    int* i_row = i_deg + (N + 16);
    int* i_cur = i_row + (N + 16);
    int* i_tmp = i_cur + (N + 16);
    int* i_par = i_tmp + (N + 16);
    int* i_csr = i_par + 2048;                            // ET ints
    ushortT* W1t = (ushortT*)(i_csr + ET);                // 256*128 bf16
    ushortT* W2t = W1t + 256 * 128;                       // 48*256 bf16
    // layer-2 overlays h1b (dead after k_agg1)
    ushortT* h2b = (ushortT*)w;                           // N*40 bf16 (8 MB)
    float* s2s = (float*)(w + (size_t)N * 40 * 2);        // N
    float* s2d = s2s + N;                                 // N

    const int nb4 = (N + 3) / 4;
    const int nbs = (N + 1023) / 1024;
    const int nbG = (N / 16 + 3) / 4;   // gemm blocks (4 waves x 16 rows)

    // ---- CSR build ----
    hipMemsetAsync(i_deg, 0, (size_t)N * sizeof(int), stream);
    k_deg<<<(ET + 255) / 256, 256, 0, stream>>>(ei, E, N, i_deg);
    k_scan_a<<<nbs, 1024, 0, stream>>>(i_deg, i_tmp, i_par, N);
    k_scan_b<<<1, 1024, 0, stream>>>(i_par, nbs);
    k_scan_c<<<(N + 255) / 256, 256, 0, stream>>>(i_deg, i_tmp, i_par, i_row, i_cur, N);
    {   // 2 dst-ranged scatter passes (write window ~3.4 MB each)
        int step = (N + 1) / 2;
        k_scatter_r<<<(ET + 255) / 256, 256, 0, stream>>>(ei, E, N, i_cur, i_csr, 0, step);
        k_scatter_r<<<(ET + 255) / 256, 256, 0, stream>>>(ei, E, N, i_cur, i_csr, step, N);
    }

    // ---- weight prep (overlaps CSR logically; same stream) ----
    k_prep<<<176, 256, 0, stream>>>(W1, W2, W1t, W2t);

    // ---- layer 1 ----
    k_gemm1<<<nbG, 256, 0, stream>>>(x, W1t, h1b, N);
    k_scores1<<<(N * 8 + 255) / 256, 256, 0, stream>>>(h1b, a1s, a1d, s1s, s1d, N * 8);
    k_agg1<<<nb4, 256, 0, stream>>>(h1b, s1s, s1d, i_row, i_csr, b1, out1b, N);

    // ---- layer 2 ----
    k_gemm2<<<nbG, 256, 0, stream>>>(out1b, W2t, a2s, a2d, h2b, s2s, s2d, N);
    k_agg2lsm<<<nb4, 256, 0, stream>>>(h2b, s2s, s2d, i_row, i_csr, b2, out, N);
}

// Round 6
// 582.468 us; speedup vs baseline: 1.2820x; 1.1312x over previous
//
#include <hip/hip_runtime.h>
#include <hip/hip_bf16.h>
#include <cmath>

// ---------------------------------------------------------------------------
// GAT 2-layer forward.
//  - LDS-free MFMA GEMMs (A direct global->reg, B pre-transposed bf16).
//  - scores1 fused into GEMM1 as 16 extra output cols via Wa = W1 @ blockdiag(a).
//  - Inline-softmax aggregation; k_agg1: 2 edge slots x depth-2 pipeline
//    (4 gathers in flight/wave); agg2: 6 slots x depth-2.
//  - CSR counting sort; 2 dst-ranged scatter passes; log_softmax fused.
// ---------------------------------------------------------------------------

#define LEAKY(e) ((e) >= 0.f ? (e) : 0.2f * (e))

typedef unsigned short ushortT;
typedef unsigned int uintT;
typedef __attribute__((ext_vector_type(8))) short short8;
typedef __attribute__((ext_vector_type(4))) float float4v;

static __device__ __forceinline__ float bflo(uintT u) {
    return __uint_as_float(u << 16);
}
static __device__ __forceinline__ float bfhi(uintT u) {
    return __uint_as_float(u & 0xffff0000u);
}
static __device__ __forceinline__ ushortT f2bf(float f) {
    __hip_bfloat16 h = __float2bfloat16(f);   // RNE
    return *reinterpret_cast<ushortT*>(&h);
}
static __device__ __forceinline__ uintT pk(float a, float b) {
    return (uintT)f2bf(a) | ((uintT)f2bf(b) << 16);
}

// ---------------- prep: transpose weights to bf16 + score matrix -----------
// W1t: 272 rows x 128 (rows 0..255 = W1 cols; 256..263 = Wa src; 264..271 dst)
// W2t: 48 rows x 256 (cols 40..47 zero)
__global__ __launch_bounds__(256) void k_prep(const float* __restrict__ W1,
                                              const float* __restrict__ W2,
                                              const float* __restrict__ a1s,
                                              const float* __restrict__ a1d,
                                              ushortT* __restrict__ W1t,
                                              ushortT* __restrict__ W2t) {
    int t = blockIdx.x * 256 + threadIdx.x;
    if (t < 128 * 256) {
        int k = t >> 8, c = t & 255;
        W1t[c * 128 + k] = f2bf(W1[t]);
    } else if (t < 128 * 256 + 48 * 256) {
        int q = t - 128 * 256;
        int k = q / 48, c = q - k * 48;
        W2t[c * 256 + k] = (c < 40) ? f2bf(W2[k * 40 + c]) : (ushortT)0;
    } else if (t < 128 * 256 + 48 * 256 + 2048) {
        int q = t - (128 * 256 + 48 * 256);
        int k = q >> 4, j = q & 15;
        int h = j & 7;
        const float* av = ((j < 8) ? a1s : a1d) + h * 32;
        const float* wr = W1 + (size_t)k * 256 + h * 32;
        float s = 0.f;
        #pragma unroll
        for (int c = 0; c < 32; ++c) s += wr[c] * av[c];
        W1t[(256 + j) * 128 + k] = f2bf(s);
    }
}

// ---------------- GEMM1: x[M,128] @ W1 -> bf16 h1b[M,256] + fused scores ---
__global__ __launch_bounds__(256) void k_gemm1(const float* __restrict__ A,
                                               const ushortT* __restrict__ Bt,
                                               ushortT* __restrict__ C,
                                               float* __restrict__ s1s,
                                               float* __restrict__ s1d, int M) {
    int lane = threadIdx.x & 63, wave = threadIdx.x >> 6;
    int slab = blockIdx.x * 4 + wave;
    int r0 = slab * 16;
    if (r0 >= M) return;
    int n = lane & 15, q = lane >> 4;
    const float* arow = A + (size_t)(r0 + n) * 128 + q * 8;
    short8 af[4];
    #pragma unroll
    for (int s = 0; s < 4; ++s) {
        float4 v0 = *(const float4*)(arow + s * 32);
        float4 v1 = *(const float4*)(arow + s * 32 + 4);
        short8 a;
        a[0] = (short)f2bf(v0.x); a[1] = (short)f2bf(v0.y);
        a[2] = (short)f2bf(v0.z); a[3] = (short)f2bf(v0.w);
        a[4] = (short)f2bf(v1.x); a[5] = (short)f2bf(v1.y);
        a[6] = (short)f2bf(v1.z); a[7] = (short)f2bf(v1.w);
        af[s] = a;
    }
    float4v acc[17];
    #pragma unroll
    for (int j = 0; j < 17; ++j) acc[j] = (float4v){0.f, 0.f, 0.f, 0.f};
    #pragma unroll
    for (int s = 0; s < 4; ++s) {
        #pragma unroll
        for (int j = 0; j < 17; ++j) {
            short8 b = *(const short8*)(Bt + (size_t)(j * 16 + n) * 128 + s * 32 + q * 8);
            acc[j] = __builtin_amdgcn_mfma_f32_16x16x32_bf16(af[s], b, acc[j], 0, 0, 0);
        }
    }
    #pragma unroll
    for (int j = 0; j < 16; ++j) {
        int col = j * 16 + n;
        #pragma unroll
        for (int r = 0; r < 4; ++r)
            C[(size_t)(r0 + q * 4 + r) * 256 + col] = f2bf(acc[j][r]);
    }
    // score tile (j=16): col' = n; n<8 -> s_src head n, n>=8 -> s_dst head n-8
    #pragma unroll
    for (int r = 0; r < 4; ++r) {
        int row = r0 + q * 4 + r;
        float vv = acc[16][r];
        if (n < 8) s1s[(size_t)row * 8 + n] = vv;
        else       s1d[(size_t)row * 8 + (n - 8)] = vv;
    }
}

// ---------------- CSR build ------------------------------------------------
__global__ __launch_bounds__(256) void k_deg(const int* __restrict__ ei, int E, int N,
                                             int* __restrict__ deg) {
    int e = blockIdx.x * blockDim.x + threadIdx.x;
    int total = E + N;
    if (e >= total) return;
    int dst = (e < E) ? ei[E + e] : (e - E);
    atomicAdd(&deg[dst], 1);
}

__global__ __launch_bounds__(1024) void k_scan_a(const int* __restrict__ deg,
                                                 int* __restrict__ tmp,
                                                 int* __restrict__ part, int n) {
    __shared__ int wsum[16];
    int t = threadIdx.x, lane = t & 63, wv = t >> 6;
    int i = blockIdx.x * 1024 + t;
    int v = (i < n) ? deg[i] : 0;
    int incl = v;
    #pragma unroll
    for (int off = 1; off < 64; off <<= 1) {
        int u = __shfl_up(incl, off, 64);
        if (lane >= off) incl += u;
    }
    if (lane == 63) wsum[wv] = incl;
    __syncthreads();
    if (wv == 0) {
        int s = (lane < 16) ? wsum[lane] : 0;
        #pragma unroll
        for (int off = 1; off < 16; off <<= 1) {
            int u = __shfl_up(s, off, 64);
            if (lane >= off) s += u;
        }
        if (lane < 16) wsum[lane] = s;
    }
    __syncthreads();
    int g = incl + (wv ? wsum[wv - 1] : 0);
    if (i < n) tmp[i] = g;
    if (t == 1023) part[blockIdx.x] = g;
}

__global__ __launch_bounds__(1024) void k_scan_b(int* __restrict__ part, int nb) {
    __shared__ int wsum[16];
    int t = threadIdx.x, lane = t & 63, wv = t >> 6;
    int v = (t < nb) ? part[t] : 0;
    int incl = v;
    #pragma unroll
    for (int off = 1; off < 64; off <<= 1) {
        int u = __shfl_up(incl, off, 64);
        if (lane >= off) incl += u;
    }
    if (lane == 63) wsum[wv] = incl;
    __syncthreads();
    if (wv == 0) {
        int s = (lane < 16) ? wsum[lane] : 0;
        #pragma unroll
        for (int off = 1; off < 16; off <<= 1) {
            int u = __shfl_up(s, off, 64);
            if (lane >= off) s += u;
        }
        if (lane < 16) wsum[lane] = s;
    }
    __syncthreads();
    int g = incl + (wv ? wsum[wv - 1] : 0);
    if (t < nb) part[t] = g;
}

__global__ __launch_bounds__(256) void k_scan_c(const int* __restrict__ deg,
                                                const int* __restrict__ tmp,
                                                const int* __restrict__ part,
                                                int* __restrict__ rowptr,
                                                int* __restrict__ cursor, int n) {
    int i = blockIdx.x * blockDim.x + threadIdx.x;
    if (i >= n) return;
    int b = i >> 10;
    int off = b ? part[b - 1] : 0;
    int incl = tmp[i] + off;
    rowptr[i + 1] = incl;
    cursor[i] = incl - deg[i];
    if (i == 0) rowptr[0] = 0;
}

__global__ __launch_bounds__(256) void k_scatter_r(const int* __restrict__ ei, int E, int N,
                                                   int* __restrict__ cursor,
                                                   int* __restrict__ csr_src,
                                                   int lo, int hi) {
    int e = blockIdx.x * blockDim.x + threadIdx.x;
    int total = E + N;
    if (e >= total) return;
    int dst = (e < E) ? ei[E + e] : (e - E);
    if (dst < lo || dst >= hi) return;
    int src = (e < E) ? ei[e] : dst;
    int pos = atomicAdd(&cursor[dst], 1);
    csr_src[pos] = src;
}

// ---------------- layer-1 aggregation: 2 edge slots x depth-2 pipeline -----
// wave per dst node; 32 lanes per edge (8 ch each via uint4); inline softmax.
__global__ __launch_bounds__(256) void k_agg1(const ushortT* __restrict__ h1,
                                              const float* __restrict__ ssrc,
                                              const float* __restrict__ sdst,
                                              const int* __restrict__ rowptr,
                                              const int* __restrict__ csr_src,
                                              const float* __restrict__ b1,
                                              ushortT* __restrict__ out1, int N) {
    int lane = threadIdx.x & 63;
    int wid = threadIdx.x >> 6;
    int n = blockIdx.x * 4 + wid;
    if (n >= N) return;
    int slot = lane >> 5;        // edge parity
    int cl = lane & 31;          // 8 channels each
    int head = cl >> 2;
    int beg = rowptr[n], end = rowptr[n + 1];
    float sdn = sdst[(size_t)n * 8 + head];
    const ushortT* hb = h1 + cl * 8;
    float a0 = 0.f, a1 = 0.f, a2 = 0.f, a3 = 0.f;
    float a4 = 0.f, a5 = 0.f, a6 = 0.f, a7 = 0.f, l = 0.f;
    int i0 = beg + slot;
    float sv0 = 0.f, sv1 = 0.f;
    uint4 v0 = make_uint4(0u, 0u, 0u, 0u), v1 = v0;
    if (i0 < end) {
        int s = csr_src[i0];
        sv0 = ssrc[(size_t)s * 8 + head];
        v0 = *(const uint4*)(hb + (size_t)s * 256);
    }
    if (i0 + 2 < end) {
        int s = csr_src[i0 + 2];
        sv1 = ssrc[(size_t)s * 8 + head];
        v1 = *(const uint4*)(hb + (size_t)s * 256);
    }
    for (int idx = i0; idx < end; idx += 2) {
        float sv = sv0; uint4 v = v0;
        sv0 = sv1; v0 = v1;
        int i2 = idx + 4;
        if (i2 < end) {
            int s = csr_src[i2];
            sv1 = ssrc[(size_t)s * 8 + head];
            v1 = *(const uint4*)(hb + (size_t)s * 256);
        }
        float p = __expf(LEAKY(sv + sdn));
        l += p;
        a0 += p * bflo(v.x); a1 += p * bfhi(v.x);
        a2 += p * bflo(v.y); a3 += p * bfhi(v.y);
        a4 += p * bflo(v.z); a5 += p * bfhi(v.z);
        a6 += p * bflo(v.w); a7 += p * bfhi(v.w);
    }
    a0 += __shfl_xor(a0, 32, 64); a1 += __shfl_xor(a1, 32, 64);
    a2 += __shfl_xor(a2, 32, 64); a3 += __shfl_xor(a3, 32, 64);
    a4 += __shfl_xor(a4, 32, 64); a5 += __shfl_xor(a5, 32, 64);
    a6 += __shfl_xor(a6, 32, 64); a7 += __shfl_xor(a7, 32, 64);
    l += __shfl_xor(l, 32, 64);
    if (slot == 0) {
        float inv = 1.f / l;
        const float4 bb0 = *(const float4*)(b1 + cl * 8);
        const float4 bb1 = *(const float4*)(b1 + cl * 8 + 4);
        uint4 o;
        o.x = pk(fmaxf(a0 * inv + bb0.x, 0.f), fmaxf(a1 * inv + bb0.y, 0.f));
        o.y = pk(fmaxf(a2 * inv + bb0.z, 0.f), fmaxf(a3 * inv + bb0.w, 0.f));
        o.z = pk(fmaxf(a4 * inv + bb1.x, 0.f), fmaxf(a5 * inv + bb1.y, 0.f));
        o.w = pk(fmaxf(a6 * inv + bb1.z, 0.f), fmaxf(a7 * inv + bb1.w, 0.f));
        *(uint4*)(out1 + (size_t)n * 256 + cl * 8) = o;
    }
}

// ---------------- GEMM2: out1b[M,256] @ W2 -> bf16 h2b[M,40] + scores2 -----
__global__ __launch_bounds__(256) void k_gemm2(const ushortT* __restrict__ X,
                                               const ushortT* __restrict__ Bt,
                                               const float* __restrict__ a2s,
                                               const float* __restrict__ a2d,
                                               ushortT* __restrict__ H2,
                                               float* __restrict__ s2s,
                                               float* __restrict__ s2d, int M) {
    int lane = threadIdx.x & 63, wave = threadIdx.x >> 6;
    int slab = blockIdx.x * 4 + wave;
    int r0 = slab * 16;
    if (r0 >= M) return;
    int n = lane & 15, q = lane >> 4;
    const ushortT* xrow = X + (size_t)(r0 + n) * 256 + q * 8;
    float4v acc[3];
    #pragma unroll
    for (int j = 0; j < 3; ++j) acc[j] = (float4v){0.f, 0.f, 0.f, 0.f};
    #pragma unroll
    for (int s = 0; s < 8; ++s) {
        short8 a = *(const short8*)(xrow + s * 32);
        #pragma unroll
        for (int j = 0; j < 3; ++j) {
            short8 b = *(const short8*)(Bt + (size_t)(j * 16 + n) * 256 + s * 32 + q * 8);
            acc[j] = __builtin_amdgcn_mfma_f32_16x16x32_bf16(a, b, acc[j], 0, 0, 0);
        }
    }
    float asv[3], adv[3];
    #pragma unroll
    for (int j = 0; j < 3; ++j) {
        int col = j * 16 + n;
        asv[j] = (col < 40) ? a2s[col] : 0.f;
        adv[j] = (col < 40) ? a2d[col] : 0.f;
    }
    float us[4], ud[4];
    #pragma unroll
    for (int r = 0; r < 4; ++r) {
        us[r] = acc[0][r] * asv[0] + acc[1][r] * asv[1] + acc[2][r] * asv[2];
        ud[r] = acc[0][r] * adv[0] + acc[1][r] * adv[1] + acc[2][r] * adv[2];
    }
    #pragma unroll
    for (int off = 1; off < 16; off <<= 1) {
        #pragma unroll
        for (int r = 0; r < 4; ++r) {
            us[r] += __shfl_xor(us[r], off, 64);
            ud[r] += __shfl_xor(ud[r], off, 64);
        }
    }
    #pragma unroll
    for (int j = 0; j < 3; ++j) {
        int col = j * 16 + n;
        if (col < 40) {
            #pragma unroll
            for (int r = 0; r < 4; ++r)
                H2[(size_t)(r0 + q * 4 + r) * 40 + col] = f2bf(acc[j][r]);
        }
    }
    if (n == 0) {
        #pragma unroll
        for (int r = 0; r < 4; ++r) {
            int row = r0 + q * 4 + r;
            s2s[row] = us[r];
            s2d[row] = ud[r];
        }
    }
}

// ---------------- layer-2 aggregation + log_softmax (depth-2 pipeline) -----
__global__ __launch_bounds__(256) void k_agg2lsm(const ushortT* __restrict__ h2,
                                                 const float* __restrict__ ss,
                                                 const float* __restrict__ sd,
                                                 const int* __restrict__ rowptr,
                                                 const int* __restrict__ csr_src,
                                                 const float* __restrict__ b2,
                                                 float* __restrict__ out, int N) {
    int lane = threadIdx.x & 63;
    int wid = threadIdx.x >> 6;
    int n = blockIdx.x * 4 + wid;
    if (n >= N) return;
    int el = lane / 10;
    int cl = lane - el * 10;
    int beg = rowptr[n], end = rowptr[n + 1];
    float sdn = sd[n];
    float a0 = 0.f, a1 = 0.f, a2 = 0.f, a3 = 0.f, l = 0.f;
    if (el < 6) {
        int ia = beg + el;
        float sv0 = 0.f, sv1 = 0.f;
        uint2 v0 = make_uint2(0u, 0u), v1 = v0;
        if (ia < end) {
            int s = csr_src[ia];
            sv0 = ss[s];
            v0 = *(const uint2*)(h2 + (size_t)s * 40 + cl * 4);
        }
        if (ia + 6 < end) {
            int s = csr_src[ia + 6];
            sv1 = ss[s];
            v1 = *(const uint2*)(h2 + (size_t)s * 40 + cl * 4);
        }
        for (int idx = ia; idx < end; idx += 6) {
            float sv = sv0; uint2 v = v0;
            sv0 = sv1; v0 = v1;
            int i2 = idx + 12;
            if (i2 < end) {
                int s = csr_src[i2];
                sv1 = ss[s];
                v1 = *(const uint2*)(h2 + (size_t)s * 40 + cl * 4);
            }
            float p = __expf(LEAKY(sv + sdn));
            l += p;
            a0 += p * bflo(v.x); a1 += p * bfhi(v.x);
            a2 += p * bflo(v.y); a3 += p * bfhi(v.y);
        }
    }
    // reduce the 6 slots into lanes 0..9
    float t0 = 0.f, t1 = 0.f, t2 = 0.f, t3 = 0.f, lt = 0.f;
    #pragma unroll
    for (int k = 0; k < 6; ++k) {
        int sl = cl + 10 * k;
        t0 += __shfl(a0, sl, 64);
        t1 += __shfl(a1, sl, 64);
        t2 += __shfl(a2, sl, 64);
        t3 += __shfl(a3, sl, 64);
        if (cl == 0) lt += __shfl(l, sl, 64);
    }
    lt = __shfl(lt, 0, 64);   // lane 0 (cl==0) holds the full denominator
    float inv = 1.f / lt;
    float o0 = t0 * inv + b2[cl * 4 + 0];
    float o1 = t1 * inv + b2[cl * 4 + 1];
    float o2 = t2 * inv + b2[cl * 4 + 2];
    float o3 = t3 * inv + b2[cl * 4 + 3];
    float lm = (lane < 10) ? fmaxf(fmaxf(o0, o1), fmaxf(o2, o3)) : -INFINITY;
    #pragma unroll
    for (int off = 32; off; off >>= 1) lm = fmaxf(lm, __shfl_xor(lm, off, 64));
    float le = (lane < 10)
        ? __expf(o0 - lm) + __expf(o1 - lm) + __expf(o2 - lm) + __expf(o3 - lm)
        : 0.f;
    #pragma unroll
    for (int off = 32; off; off >>= 1) le += __shfl_xor(le, off, 64);
    float ls = lm + logf(le);
    if (lane < 10) {
        float4 w = make_float4(o0 - ls, o1 - ls, o2 - ls, o3 - ls);
        *(float4*)(out + (size_t)n * 40 + cl * 4) = w;
    }
}

// ---------------------------------------------------------------------------
extern "C" void kernel_launch(void* const* d_in, const int* in_sizes, int n_in,
                              void* d_out, int out_size, void* d_ws, size_t ws_size,
                              hipStream_t stream) {
    const float* x   = (const float*)d_in[0];
    const int*   ei  = (const int*)d_in[1];
    const float* W1  = (const float*)d_in[2];
    const float* a1s = (const float*)d_in[3];
    const float* a1d = (const float*)d_in[4];
    const float* b1  = (const float*)d_in[5];
    const float* W2  = (const float*)d_in[6];
    const float* a2s = (const float*)d_in[7];
    const float* a2d = (const float*)d_in[8];
    const float* b2  = (const float*)d_in[9];
    float* out = (float*)d_out;

    const int N = in_sizes[0] / 128;   // 100000
    const int E = in_sizes[1] / 2;     // 1600000
    const int ET = E + N;

    // ---- workspace layout ----
    char* w = (char*)d_ws;
    ushortT* h1b   = (ushortT*)w;                         // N*256 bf16 (51.2 MB)
    ushortT* out1b = h1b + (size_t)N * 256;               // N*256 bf16 (51.2 MB)
    float* s1s  = (float*)(out1b + (size_t)N * 256);      // N*8
    float* s1d  = s1s + (size_t)N * 8;
    int* i_deg = (int*)(s1d + (size_t)N * 8);
    int* i_row = i_deg + (N + 16);
    int* i_cur = i_row + (N + 16);
    int* i_tmp = i_cur + (N + 16);
    int* i_par = i_tmp + (N + 16);
    int* i_csr = i_par + 2048;                            // ET ints
    ushortT* W1t = (ushortT*)(i_csr + ET);                // 272*128 bf16
    ushortT* W2t = W1t + 272 * 128;                       // 48*256 bf16
    // layer-2 overlays h1b (dead after k_agg1)
    ushortT* h2b = (ushortT*)w;                           // N*40 bf16 (8 MB)
    float* s2s = (float*)(w + (size_t)N * 40 * 2);        // N
    float* s2d = s2s + N;                                 // N

    const int nb4 = (N + 3) / 4;
    const int nbs = (N + 1023) / 1024;
    const int nbG = (N / 16 + 3) / 4;   // gemm blocks (4 waves x 16 rows)

    // ---- CSR build ----
    hipMemsetAsync(i_deg, 0, (size_t)N * sizeof(int), stream);
    k_deg<<<(ET + 255) / 256, 256, 0, stream>>>(ei, E, N, i_deg);
    k_scan_a<<<nbs, 1024, 0, stream>>>(i_deg, i_tmp, i_par, N);
    k_scan_b<<<1, 1024, 0, stream>>>(i_par, nbs);
    k_scan_c<<<(N + 255) / 256, 256, 0, stream>>>(i_deg, i_tmp, i_par, i_row, i_cur, N);
    {   // 2 dst-ranged scatter passes (write window ~3.4 MB each)
        int step = (N + 1) / 2;
        k_scatter_r<<<(ET + 255) / 256, 256, 0, stream>>>(ei, E, N, i_cur, i_csr, 0, step);
        k_scatter_r<<<(ET + 255) / 256, 256, 0, stream>>>(ei, E, N, i_cur, i_csr, step, N);
    }

    // ---- weight prep ----
    k_prep<<<184, 256, 0, stream>>>(W1, W2, a1s, a1d, W1t, W2t);

    // ---- layer 1 ----
    k_gemm1<<<nbG, 256, 0, stream>>>(x, W1t, h1b, s1s, s1d, N);
    k_agg1<<<nb4, 256, 0, stream>>>(h1b, s1s, s1d, i_row, i_csr, b1, out1b, N);

    // ---- layer 2 ----
    k_gemm2<<<nbG, 256, 0, stream>>>(out1b, W2t, a2s, a2d, h2b, s2s, s2d, N);
    k_agg2lsm<<<nb4, 256, 0, stream>>>(h2b, s2s, s2d, i_row, i_csr, b2, out, N);
}

// Round 7
// 543.317 us; speedup vs baseline: 1.3744x; 1.0721x over previous
//
#include <hip/hip_runtime.h>
#include <hip/hip_bf16.h>
#include <cmath>

// ---------------------------------------------------------------------------
// GAT 2-layer forward.
//  - LDS-free MFMA GEMMs (A direct global->reg, B pre-transposed bf16).
//  - scores1 fused into GEMM1 (extra 16 output cols via Wa = W1 @ blockdiag(a)).
//  - h1 stored INT8 with per-row scale (gemm1 col-tiling permuted so each lane
//    holds 16 consecutive channels -> coalesced uint4 int8 stores, natural
//    channel order). agg1 gathers 256 B/edge instead of 512.
//  - Inline-softmax aggregation, depth-3 software pipelines.
//  - CSR counting sort; self-loops placed during scan; 2 dst-ranged scatters.
//  - scores2 fused into GEMM2; log_softmax fused into agg2.
// ---------------------------------------------------------------------------

#define LEAKY(e) ((e) >= 0.f ? (e) : 0.2f * (e))

typedef unsigned short ushortT;
typedef unsigned int uintT;
typedef unsigned char ucharT;
typedef __attribute__((ext_vector_type(8))) short short8;
typedef __attribute__((ext_vector_type(4))) float float4v;

static __device__ __forceinline__ float bflo(uintT u) {
    return __uint_as_float(u << 16);
}
static __device__ __forceinline__ float bfhi(uintT u) {
    return __uint_as_float(u & 0xffff0000u);
}
static __device__ __forceinline__ ushortT f2bf(float f) {
    __hip_bfloat16 h = __float2bfloat16(f);   // RNE
    return *reinterpret_cast<ushortT*>(&h);
}
static __device__ __forceinline__ uintT pk(float a, float b) {
    return (uintT)f2bf(a) | ((uintT)f2bf(b) << 16);
}
static __device__ __forceinline__ float sb(uintT u, int k) {   // signed byte k
    return (float)((int)(u << (24 - 8 * k)) >> 24);
}

// ---------------- prep: transpose weights to bf16 + score matrix -----------
// W1t rows 0..255: storage row s=j*16+n holds W1 col (16n+j) [permuted tiling]
// W1t rows 256..271: Wa (scores);  W2t: 48 x 256 (cols 40..47 zero)
__global__ __launch_bounds__(256) void k_prep(const float* __restrict__ W1,
                                              const float* __restrict__ W2,
                                              const float* __restrict__ a1s,
                                              const float* __restrict__ a1d,
                                              ushortT* __restrict__ W1t,
                                              ushortT* __restrict__ W2t) {
    int t = blockIdx.x * 256 + threadIdx.x;
    if (t < 128 * 256) {
        int k = t >> 8, s = t & 255;
        int c = ((s & 15) << 4) | (s >> 4);
        W1t[s * 128 + k] = f2bf(W1[(size_t)k * 256 + c]);
    } else if (t < 128 * 256 + 48 * 256) {
        int q = t - 128 * 256;
        int k = q / 48, c = q - k * 48;
        W2t[c * 256 + k] = (c < 40) ? f2bf(W2[k * 40 + c]) : (ushortT)0;
    } else if (t < 128 * 256 + 48 * 256 + 2048) {
        int q = t - (128 * 256 + 48 * 256);
        int k = q >> 4, j = q & 15;
        int h = j & 7;
        const float* av = ((j < 8) ? a1s : a1d) + h * 32;
        const float* wr = W1 + (size_t)k * 256 + h * 32;
        float s = 0.f;
        #pragma unroll
        for (int c = 0; c < 32; ++c) s += wr[c] * av[c];
        W1t[(256 + j) * 128 + k] = f2bf(s);
    }
}

// ---------------- GEMM1: x[M,128] @ W1 -> int8 h1i[M,256] + scale + scores -
__global__ __launch_bounds__(256) void k_gemm1(const float* __restrict__ A,
                                               const ushortT* __restrict__ Bt,
                                               ucharT* __restrict__ h1i,
                                               float* __restrict__ hsc,
                                               float* __restrict__ s1s,
                                               float* __restrict__ s1d, int M) {
    int lane = threadIdx.x & 63, wave = threadIdx.x >> 6;
    int slab = blockIdx.x * 4 + wave;
    int r0 = slab * 16;
    if (r0 >= M) return;
    int n = lane & 15, q = lane >> 4;
    const float* arow = A + (size_t)(r0 + n) * 128 + q * 8;
    short8 af[4];
    #pragma unroll
    for (int s = 0; s < 4; ++s) {
        float4 v0 = *(const float4*)(arow + s * 32);
        float4 v1 = *(const float4*)(arow + s * 32 + 4);
        short8 a;
        a[0] = (short)f2bf(v0.x); a[1] = (short)f2bf(v0.y);
        a[2] = (short)f2bf(v0.z); a[3] = (short)f2bf(v0.w);
        a[4] = (short)f2bf(v1.x); a[5] = (short)f2bf(v1.y);
        a[6] = (short)f2bf(v1.z); a[7] = (short)f2bf(v1.w);
        af[s] = a;
    }
    float4v acc[17];
    #pragma unroll
    for (int j = 0; j < 17; ++j) acc[j] = (float4v){0.f, 0.f, 0.f, 0.f};
    #pragma unroll
    for (int s = 0; s < 4; ++s) {
        #pragma unroll
        for (int j = 0; j < 17; ++j) {
            short8 b = *(const short8*)(Bt + (size_t)(j * 16 + n) * 128 + s * 32 + q * 8);
            acc[j] = __builtin_amdgcn_mfma_f32_16x16x32_bf16(af[s], b, acc[j], 0, 0, 0);
        }
    }
    // acc[j][r] = value for row (r0+q*4+r), ORIGINAL col (16n + j)
    float am[4];
    #pragma unroll
    for (int r = 0; r < 4; ++r) {
        float m = 0.f;
        #pragma unroll
        for (int j = 0; j < 16; ++j) m = fmaxf(m, fabsf(acc[j][r]));
        am[r] = m;
    }
    #pragma unroll
    for (int off = 1; off < 16; off <<= 1) {
        #pragma unroll
        for (int r = 0; r < 4; ++r) am[r] = fmaxf(am[r], __shfl_xor(am[r], off, 64));
    }
    #pragma unroll
    for (int r = 0; r < 4; ++r) {
        int row = r0 + q * 4 + r;
        float m = am[r];
        float si = (m > 0.f) ? 127.f / m : 0.f;
        uintT wd[4];
        #pragma unroll
        for (int wq = 0; wq < 4; ++wq) {
            uintT p4 = 0;
            #pragma unroll
            for (int b = 0; b < 4; ++b) {
                int j = wq * 4 + b;
                int qv = (int)rintf(acc[j][r] * si);
                p4 |= ((uintT)(qv & 0xff)) << (8 * b);
            }
            wd[wq] = p4;
        }
        uint4 o = make_uint4(wd[0], wd[1], wd[2], wd[3]);
        *(uint4*)(h1i + (size_t)row * 256 + n * 16) = o;
        if (n == 0) hsc[row] = m * (1.f / 127.f);
        float vv = acc[16][r];
        if (n < 8) s1s[(size_t)row * 8 + n] = vv;
        else       s1d[(size_t)row * 8 + (n - 8)] = vv;
    }
}

// ---------------- CSR build ------------------------------------------------
__global__ __launch_bounds__(256) void k_deg(const int* __restrict__ ei, int E,
                                             int* __restrict__ deg) {
    int e4 = (blockIdx.x * 256 + threadIdx.x) * 4;
    if (e4 + 3 < E) {
        int4 d = *(const int4*)(ei + E + e4);
        atomicAdd(&deg[d.x], 1);
        atomicAdd(&deg[d.y], 1);
        atomicAdd(&deg[d.z], 1);
        atomicAdd(&deg[d.w], 1);
    } else {
        for (int e = e4; e < E; ++e) atomicAdd(&deg[ei[E + e]], 1);
    }
}

__global__ __launch_bounds__(1024) void k_scan_a(const int* __restrict__ deg,
                                                 int* __restrict__ tmp,
                                                 int* __restrict__ part, int n) {
    __shared__ int wsum[16];
    int t = threadIdx.x, lane = t & 63, wv = t >> 6;
    int i = blockIdx.x * 1024 + t;
    int v = (i < n) ? (deg[i] + 1) : 0;   // +1 = self loop
    int incl = v;
    #pragma unroll
    for (int off = 1; off < 64; off <<= 1) {
        int u = __shfl_up(incl, off, 64);
        if (lane >= off) incl += u;
    }
    if (lane == 63) wsum[wv] = incl;
    __syncthreads();
    if (wv == 0) {
        int s = (lane < 16) ? wsum[lane] : 0;
        #pragma unroll
        for (int off = 1; off < 16; off <<= 1) {
            int u = __shfl_up(s, off, 64);
            if (lane >= off) s += u;
        }
        if (lane < 16) wsum[lane] = s;
    }
    __syncthreads();
    int g = incl + (wv ? wsum[wv - 1] : 0);
    if (i < n) tmp[i] = g;
    if (t == 1023) part[blockIdx.x] = g;
}

__global__ __launch_bounds__(1024) void k_scan_b(int* __restrict__ part, int nb) {
    __shared__ int wsum[16];
    int t = threadIdx.x, lane = t & 63, wv = t >> 6;
    int v = (t < nb) ? part[t] : 0;
    int incl = v;
    #pragma unroll
    for (int off = 1; off < 64; off <<= 1) {
        int u = __shfl_up(incl, off, 64);
        if (lane >= off) incl += u;
    }
    if (lane == 63) wsum[wv] = incl;
    __syncthreads();
    if (wv == 0) {
        int s = (lane < 16) ? wsum[lane] : 0;
        #pragma unroll
        for (int off = 1; off < 16; off <<= 1) {
            int u = __shfl_up(s, off, 64);
            if (lane >= off) s += u;
        }
        if (lane < 16) wsum[lane] = s;
    }
    __syncthreads();
    int g = incl + (wv ? wsum[wv - 1] : 0);
    if (t < nb) part[t] = g;
}

__global__ __launch_bounds__(256) void k_scan_c(const int* __restrict__ deg,
                                                const int* __restrict__ tmp,
                                                const int* __restrict__ part,
                                                int* __restrict__ rowptr,
                                                int* __restrict__ cursor,
                                                int* __restrict__ csr_src, int n) {
    int i = blockIdx.x * blockDim.x + threadIdx.x;
    if (i >= n) return;
    int b = i >> 10;
    int off = b ? part[b - 1] : 0;
    int incl = tmp[i] + off;
    rowptr[i + 1] = incl;
    int start = incl - (deg[i] + 1);
    csr_src[start] = i;        // self loop pre-placed
    cursor[i] = start + 1;
    if (i == 0) rowptr[0] = 0;
}

__global__ __launch_bounds__(256) void k_scatter_r(const int* __restrict__ ei, int E,
                                                   int* __restrict__ cursor,
                                                   int* __restrict__ csr_src,
                                                   int lo, int hi) {
    int e = blockIdx.x * blockDim.x + threadIdx.x;
    if (e >= E) return;
    int dst = ei[E + e];
    if (dst < lo || dst >= hi) return;
    int pos = atomicAdd(&cursor[dst], 1);
    csr_src[pos] = ei[e];
}

// ---------------- layer-1 aggregation: int8 values, 2 slots x depth-3 ------
__global__ __launch_bounds__(256) void k_agg1(const ucharT* __restrict__ h1i,
                                              const float* __restrict__ hsc,
                                              const float* __restrict__ ssrc,
                                              const float* __restrict__ sdst,
                                              const int* __restrict__ rowptr,
                                              const int* __restrict__ csr_src,
                                              const float* __restrict__ b1,
                                              ushortT* __restrict__ out1, int N) {
    int lane = threadIdx.x & 63;
    int wid = threadIdx.x >> 6;
    int n = blockIdx.x * 4 + wid;
    if (n >= N) return;
    int slot = lane >> 5;        // edge parity
    int cl = lane & 31;          // 8 channels each (int8)
    int head = cl >> 2;
    int beg = rowptr[n], end = rowptr[n + 1];
    float sdn = sdst[(size_t)n * 8 + head];
    const ucharT* hb = h1i + cl * 8;
    float a0 = 0.f, a1 = 0.f, a2 = 0.f, a3 = 0.f;
    float a4 = 0.f, a5 = 0.f, a6 = 0.f, a7 = 0.f, l = 0.f;
    int i0 = beg + slot;
    float sv0 = 0.f, sv1 = 0.f, sv2 = 0.f;
    float sc0 = 0.f, sc1 = 0.f, sc2 = 0.f;
    uint2 v0 = make_uint2(0u, 0u), v1 = v0, v2 = v0;
    if (i0 < end) {
        int s = csr_src[i0];
        sv0 = ssrc[(size_t)s * 8 + head]; sc0 = hsc[s];
        v0 = *(const uint2*)(hb + (size_t)s * 256);
    }
    if (i0 + 2 < end) {
        int s = csr_src[i0 + 2];
        sv1 = ssrc[(size_t)s * 8 + head]; sc1 = hsc[s];
        v1 = *(const uint2*)(hb + (size_t)s * 256);
    }
    if (i0 + 4 < end) {
        int s = csr_src[i0 + 4];
        sv2 = ssrc[(size_t)s * 8 + head]; sc2 = hsc[s];
        v2 = *(const uint2*)(hb + (size_t)s * 256);
    }
    for (int idx = i0; idx < end; idx += 2) {
        float sv = sv0, sc = sc0; uint2 v = v0;
        sv0 = sv1; sc0 = sc1; v0 = v1;
        sv1 = sv2; sc1 = sc2; v1 = v2;
        int i6 = idx + 6;
        if (i6 < end) {
            int s = csr_src[i6];
            sv2 = ssrc[(size_t)s * 8 + head]; sc2 = hsc[s];
            v2 = *(const uint2*)(hb + (size_t)s * 256);
        }
        float p = __expf(LEAKY(sv + sdn));
        l += p;
        float ps = p * sc;
        a0 += ps * sb(v.x, 0); a1 += ps * sb(v.x, 1);
        a2 += ps * sb(v.x, 2); a3 += ps * sb(v.x, 3);
        a4 += ps * sb(v.y, 0); a5 += ps * sb(v.y, 1);
        a6 += ps * sb(v.y, 2); a7 += ps * sb(v.y, 3);
    }
    a0 += __shfl_xor(a0, 32, 64); a1 += __shfl_xor(a1, 32, 64);
    a2 += __shfl_xor(a2, 32, 64); a3 += __shfl_xor(a3, 32, 64);
    a4 += __shfl_xor(a4, 32, 64); a5 += __shfl_xor(a5, 32, 64);
    a6 += __shfl_xor(a6, 32, 64); a7 += __shfl_xor(a7, 32, 64);
    l += __shfl_xor(l, 32, 64);
    if (slot == 0) {
        float inv = 1.f / l;
        const float4 bb0 = *(const float4*)(b1 + cl * 8);
        const float4 bb1 = *(const float4*)(b1 + cl * 8 + 4);
        uint4 o;
        o.x = pk(fmaxf(a0 * inv + bb0.x, 0.f), fmaxf(a1 * inv + bb0.y, 0.f));
        o.y = pk(fmaxf(a2 * inv + bb0.z, 0.f), fmaxf(a3 * inv + bb0.w, 0.f));
        o.z = pk(fmaxf(a4 * inv + bb1.x, 0.f), fmaxf(a5 * inv + bb1.y, 0.f));
        o.w = pk(fmaxf(a6 * inv + bb1.z, 0.f), fmaxf(a7 * inv + bb1.w, 0.f));
        *(uint4*)(out1 + (size_t)n * 256 + cl * 8) = o;
    }
}

// ---------------- GEMM2: out1b[M,256] @ W2 -> bf16 h2b[M,40] + scores2 -----
__global__ __launch_bounds__(256) void k_gemm2(const ushortT* __restrict__ X,
                                               const ushortT* __restrict__ Bt,
                                               const float* __restrict__ a2s,
                                               const float* __restrict__ a2d,
                                               ushortT* __restrict__ H2,
                                               float* __restrict__ s2s,
                                               float* __restrict__ s2d, int M) {
    int lane = threadIdx.x & 63, wave = threadIdx.x >> 6;
    int slab = blockIdx.x * 4 + wave;
    int r0 = slab * 16;
    if (r0 >= M) return;
    int n = lane & 15, q = lane >> 4;
    const ushortT* xrow = X + (size_t)(r0 + n) * 256 + q * 8;
    float4v acc[3];
    #pragma unroll
    for (int j = 0; j < 3; ++j) acc[j] = (float4v){0.f, 0.f, 0.f, 0.f};
    #pragma unroll
    for (int s = 0; s < 8; ++s) {
        short8 a = *(const short8*)(xrow + s * 32);
        #pragma unroll
        for (int j = 0; j < 3; ++j) {
            short8 b = *(const short8*)(Bt + (size_t)(j * 16 + n) * 256 + s * 32 + q * 8);
            acc[j] = __builtin_amdgcn_mfma_f32_16x16x32_bf16(a, b, acc[j], 0, 0, 0);
        }
    }
    float asv[3], adv[3];
    #pragma unroll
    for (int j = 0; j < 3; ++j) {
        int col = j * 16 + n;
        asv[j] = (col < 40) ? a2s[col] : 0.f;
        adv[j] = (col < 40) ? a2d[col] : 0.f;
    }
    float us[4], ud[4];
    #pragma unroll
    for (int r = 0; r < 4; ++r) {
        us[r] = acc[0][r] * asv[0] + acc[1][r] * asv[1] + acc[2][r] * asv[2];
        ud[r] = acc[0][r] * adv[0] + acc[1][r] * adv[1] + acc[2][r] * adv[2];
    }
    #pragma unroll
    for (int off = 1; off < 16; off <<= 1) {
        #pragma unroll
        for (int r = 0; r < 4; ++r) {
            us[r] += __shfl_xor(us[r], off, 64);
            ud[r] += __shfl_xor(ud[r], off, 64);
        }
    }
    #pragma unroll
    for (int j = 0; j < 3; ++j) {
        int col = j * 16 + n;
        if (col < 40) {
            #pragma unroll
            for (int r = 0; r < 4; ++r)
                H2[(size_t)(r0 + q * 4 + r) * 40 + col] = f2bf(acc[j][r]);
        }
    }
    if (n == 0) {
        #pragma unroll
        for (int r = 0; r < 4; ++r) {
            int row = r0 + q * 4 + r;
            s2s[row] = us[r];
            s2d[row] = ud[r];
        }
    }
}

// ---------------- layer-2 aggregation + log_softmax (depth-3 pipeline) -----
__global__ __launch_bounds__(256) void k_agg2lsm(const ushortT* __restrict__ h2,
                                                 const float* __restrict__ ss,
                                                 const float* __restrict__ sd,
                                                 const int* __restrict__ rowptr,
                                                 const int* __restrict__ csr_src,
                                                 const float* __restrict__ b2,
                                                 float* __restrict__ out, int N) {
    int lane = threadIdx.x & 63;
    int wid = threadIdx.x >> 6;
    int n = blockIdx.x * 4 + wid;
    if (n >= N) return;
    int el = lane / 10;
    int cl = lane - el * 10;
    int beg = rowptr[n], end = rowptr[n + 1];
    float sdn = sd[n];
    float a0 = 0.f, a1 = 0.f, a2 = 0.f, a3 = 0.f, l = 0.f;
    if (el < 6) {
        int ia = beg + el;
        float sv0 = 0.f, sv1 = 0.f, sv2 = 0.f;
        uint2 v0 = make_uint2(0u, 0u), v1 = v0, v2 = v0;
        if (ia < end) {
            int s = csr_src[ia];
            sv0 = ss[s];
            v0 = *(const uint2*)(h2 + (size_t)s * 40 + cl * 4);
        }
        if (ia + 6 < end) {
            int s = csr_src[ia + 6];
            sv1 = ss[s];
            v1 = *(const uint2*)(h2 + (size_t)s * 40 + cl * 4);
        }
        if (ia + 12 < end) {
            int s = csr_src[ia + 12];
            sv2 = ss[s];
            v2 = *(const uint2*)(h2 + (size_t)s * 40 + cl * 4);
        }
        for (int idx = ia; idx < end; idx += 6) {
            float sv = sv0; uint2 v = v0;
            sv0 = sv1; v0 = v1;
            sv1 = sv2; v1 = v2;
            int i3 = idx + 18;
            if (i3 < end) {
                int s = csr_src[i3];
                sv2 = ss[s];
                v2 = *(const uint2*)(h2 + (size_t)s * 40 + cl * 4);
            }
            float p = __expf(LEAKY(sv + sdn));
            l += p;
            a0 += p * bflo(v.x); a1 += p * bfhi(v.x);
            a2 += p * bflo(v.y); a3 += p * bfhi(v.y);
        }
    }
    // reduce the 6 slots into lanes 0..9
    float t0 = 0.f, t1 = 0.f, t2 = 0.f, t3 = 0.f, lt = 0.f;
    #pragma unroll
    for (int k = 0; k < 6; ++k) {
        int sl = cl + 10 * k;
        t0 += __shfl(a0, sl, 64);
        t1 += __shfl(a1, sl, 64);
        t2 += __shfl(a2, sl, 64);
        t3 += __shfl(a3, sl, 64);
        if (cl == 0) lt += __shfl(l, sl, 64);
    }
    lt = __shfl(lt, 0, 64);
    float inv = 1.f / lt;
    float o0 = t0 * inv + b2[cl * 4 + 0];
    float o1 = t1 * inv + b2[cl * 4 + 1];
    float o2 = t2 * inv + b2[cl * 4 + 2];
    float o3 = t3 * inv + b2[cl * 4 + 3];
    float lm = (lane < 10) ? fmaxf(fmaxf(o0, o1), fmaxf(o2, o3)) : -INFINITY;
    #pragma unroll
    for (int off = 32; off; off >>= 1) lm = fmaxf(lm, __shfl_xor(lm, off, 64));
    float le = (lane < 10)
        ? __expf(o0 - lm) + __expf(o1 - lm) + __expf(o2 - lm) + __expf(o3 - lm)
        : 0.f;
    #pragma unroll
    for (int off = 32; off; off >>= 1) le += __shfl_xor(le, off, 64);
    float ls = lm + logf(le);
    if (lane < 10) {
        float4 w = make_float4(o0 - ls, o1 - ls, o2 - ls, o3 - ls);
        *(float4*)(out + (size_t)n * 40 + cl * 4) = w;
    }
}

// ---------------------------------------------------------------------------
extern "C" void kernel_launch(void* const* d_in, const int* in_sizes, int n_in,
                              void* d_out, int out_size, void* d_ws, size_t ws_size,
                              hipStream_t stream) {
    const float* x   = (const float*)d_in[0];
    const int*   ei  = (const int*)d_in[1];
    const float* W1  = (const float*)d_in[2];
    const float* a1s = (const float*)d_in[3];
    const float* a1d = (const float*)d_in[4];
    const float* b1  = (const float*)d_in[5];
    const float* W2  = (const float*)d_in[6];
    const float* a2s = (const float*)d_in[7];
    const float* a2d = (const float*)d_in[8];
    const float* b2  = (const float*)d_in[9];
    float* out = (float*)d_out;

    const int N = in_sizes[0] / 128;   // 100000
    const int E = in_sizes[1] / 2;     // 1600000
    const int ET = E + N;

    // ---- workspace layout ----
    char* w = (char*)d_ws;
    ucharT* h1i = (ucharT*)w;                             // N*256 int8 (25.6 MB)
    float* hsc  = (float*)(w + (size_t)N * 256);          // N f32 row scales
    ushortT* out1b = (ushortT*)(w + (size_t)N * 256 + (size_t)N * 4);  // N*256 bf16
    float* s1s  = (float*)(out1b + (size_t)N * 256);      // N*8
    float* s1d  = s1s + (size_t)N * 8;
    int* i_deg = (int*)(s1d + (size_t)N * 8);
    int* i_row = i_deg + (N + 16);
    int* i_cur = i_row + (N + 16);
    int* i_tmp = i_cur + (N + 16);
    int* i_par = i_tmp + (N + 16);
    int* i_csr = i_par + 2048;                            // ET ints
    ushortT* W1t = (ushortT*)(i_csr + ET);                // 272*128 bf16
    ushortT* W2t = W1t + 272 * 128;                       // 48*256 bf16
    // layer-2 overlays h1i (dead after k_agg1)
    ushortT* h2b = (ushortT*)w;                           // N*40 bf16 (8 MB)
    float* s2s = (float*)(w + (size_t)N * 40 * 2);        // N
    float* s2d = s2s + N;                                 // N

    const int nb4 = (N + 3) / 4;
    const int nbs = (N + 1023) / 1024;
    const int nbG = (N / 16 + 3) / 4;   // gemm blocks (4 waves x 16 rows)

    // ---- CSR build ----
    hipMemsetAsync(i_deg, 0, (size_t)N * sizeof(int), stream);
    k_deg<<<(E / 4 + 255) / 256, 256, 0, stream>>>(ei, E, i_deg);
    k_scan_a<<<nbs, 1024, 0, stream>>>(i_deg, i_tmp, i_par, N);
    k_scan_b<<<1, 1024, 0, stream>>>(i_par, nbs);
    k_scan_c<<<(N + 255) / 256, 256, 0, stream>>>(i_deg, i_tmp, i_par, i_row, i_cur, i_csr, N);
    {   // 2 dst-ranged scatter passes (write window ~3.4 MB each)
        int step = (N + 1) / 2;
        k_scatter_r<<<(E + 255) / 256, 256, 0, stream>>>(ei, E, i_cur, i_csr, 0, step);
        k_scatter_r<<<(E + 255) / 256, 256, 0, stream>>>(ei, E, i_cur, i_csr, step, N);
    }

    // ---- weight prep ----
    k_prep<<<184, 256, 0, stream>>>(W1, W2, a1s, a1d, W1t, W2t);

    // ---- layer 1 ----
    k_gemm1<<<nbG, 256, 0, stream>>>(x, W1t, h1i, hsc, s1s, s1d, N);
    k_agg1<<<nb4, 256, 0, stream>>>(h1i, hsc, s1s, s1d, i_row, i_csr, b1, out1b, N);

    // ---- layer 2 ----
    k_gemm2<<<nbG, 256, 0, stream>>>(out1b, W2t, a2s, a2d, h2b, s2s, s2d, N);
    k_agg2lsm<<<nb4, 256, 0, stream>>>(h2b, s2s, s2d, i_row, i_csr, b2, out, N);
}